// Round 1
// baseline (1683.594 us; speedup 1.0000x reference)
//
#include <hip/hip_runtime.h>

#define DI __device__ __forceinline__

typedef __attribute__((ext_vector_type(4))) float f32x4;
typedef __attribute__((ext_vector_type(8))) short s16x8;
typedef __attribute__((ext_vector_type(4))) unsigned short u16x4;

constexpr int B_ = 16, N_ = 2048, L_ = 12, C_ = 32;
constexpr int F_ = B_ * L_ * C_;              // 6144
constexpr long long NNq = (long long)N_ * N_; // 4194304
constexpr long long NFq = (long long)N_ * F_; // 12582912

DI unsigned short f2bf(float x) {
  unsigned u = __float_as_uint(x);
  u += 0x7fffu + ((u >> 16) & 1u);
  return (unsigned short)(u >> 16);
}
DI float bf2f(unsigned short h) { return __uint_as_float(((unsigned)h) << 16); }

typedef __attribute__((address_space(3))) void* lds_vp;
typedef const __attribute__((address_space(1))) void* gbl_vp;
DI void ald16(const void* g, void* l) {
  __builtin_amdgcn_global_load_lds((gbl_vp)g, (lds_vp)l, 16, 0, 0);
}

// ---------------- degree / dinv / u ----------------
__global__ void k_deg(const float* __restrict__ graphs, float* deg, float* dinv, float* uv) {
  int n = blockIdx.x, g = blockIdx.y;
  const float* row = graphs + (size_t)g * NNq + (size_t)n * N_;
  float s = 0.f;
  for (int m = threadIdx.x * 4; m < N_; m += 1024) {
    f32x4 v = *(const f32x4*)(row + m);
    s += v.x + v.y + v.z + v.w;
  }
  for (int o = 32; o; o >>= 1) s += __shfl_down(s, o);
  __shared__ float warr[4];
  int lane = threadIdx.x & 63, w = threadIdx.x >> 6;
  if (!lane) warr[w] = s;
  __syncthreads();
  if (!threadIdx.x) {
    float t = warr[0] + warr[1] + warr[2] + warr[3];
    deg[g * N_ + n] = t;
    dinv[g * N_ + n] = rsqrtf(t);
    uv[g * N_ + n] = sqrtf(t);
  }
}

__global__ void k_utu(const float* __restrict__ deg, float* scal) {
  int g = blockIdx.x;
  float s = 0.f;
  for (int n = threadIdx.x; n < N_; n += 256) s += deg[g * N_ + n];
  for (int o = 32; o; o >>= 1) s += __shfl_down(s, o);
  __shared__ float warr[4];
  int lane = threadIdx.x & 63, w = threadIdx.x >> 6;
  if (!lane) warr[w] = s;
  __syncthreads();
  if (!threadIdx.x) {
    float t = warr[0] + warr[1] + warr[2] + warr[3];
    scal[g] = t;
    scal[2 + g] = 1.f / t;
  }
}

__global__ void k_initv(float* v) {
  int i = blockIdx.x * 256 + threadIdx.x;
  int g = blockIdx.y;
  unsigned h = (unsigned)(i + g * 7919) * 2654435761u;
  h ^= h >> 16; h *= 2246822519u; h ^= h >> 13;
  float r = ((float)(h & 0xFFFFu) / 32768.f) - 1.f;
  if (r == 0.f) r = 0.5f;
  v[g * N_ + i] = r;
}

__global__ void k_buildM(const float* __restrict__ graphs, const float* __restrict__ dinv,
                         unsigned short* __restrict__ Mh) {
  int n = blockIdx.x, g = blockIdx.y;
  const float* row = graphs + (size_t)g * NNq + (size_t)n * N_;
  unsigned short* orow = Mh + (size_t)g * NNq + (size_t)n * N_;
  float dn = dinv[g * N_ + n];
  const float* dm = dinv + g * N_;
  for (int m = threadIdx.x * 4; m < N_; m += 1024) {
    f32x4 a = *(const f32x4*)(row + m);
    f32x4 d = *(const f32x4*)(dm + m);
    u16x4 o;
    o.x = f2bf(a.x * dn * d.x); o.y = f2bf(a.y * dn * d.y);
    o.z = f2bf(a.z * dn * d.z); o.w = f2bf(a.w * dn * d.w);
    *(u16x4*)(orow + m) = o;
  }
}

// ---------------- power iteration ----------------
__global__ void k_matvec(const float* __restrict__ Sp, const float* __restrict__ vin,
                         float* __restrict__ vout, float scale) {
  int g = blockIdx.y;
  int row = blockIdx.x * 4 + (threadIdx.x >> 6);
  int lane = threadIdx.x & 63;
  const float* r = Sp + (size_t)g * NNq + (size_t)row * N_;
  const float* v = vin + g * N_;
  float s = 0.f;
  for (int m = lane * 4; m < N_; m += 256) {
    f32x4 a = *(const f32x4*)(r + m);
    f32x4 b = *(const f32x4*)(v + m);
    s += a.x * b.x + a.y * b.y + a.z * b.z + a.w * b.w;
  }
  for (int o = 32; o; o >>= 1) s += __shfl_down(s, o);
  if (!lane) vout[g * N_ + row] = s * scale;
}

__global__ void k_rayleigh(const float* __restrict__ v, const float* __restrict__ y,
                           float* scal) {
  int g = blockIdx.x;
  double sn = 0.0, sd = 0.0;
  for (int i = threadIdx.x; i < N_; i += 256) {
    double a = v[g * N_ + i], b = y[g * N_ + i];
    sn += a * b; sd += a * a;
  }
  for (int o = 32; o; o >>= 1) { sn += __shfl_down(sn, o); sd += __shfl_down(sd, o); }
  __shared__ double wn[4], wd[4];
  int lane = threadIdx.x & 63, w = threadIdx.x >> 6;
  if (!lane) { wn[w] = sn; wd[w] = sd; }
  __syncthreads();
  if (!threadIdx.x) {
    double nn = wn[0] + wn[1] + wn[2] + wn[3];
    double dd = wd[0] + wd[1] + wd[2] + wd[3];
    double rho = nn / dd;
    if (!(rho > 0.0)) rho = 0.0;
    float R = (float)sqrt(rho);
    float lmax = 1.f + R;
    scal[4 + 2 * g] = 2.f / lmax - 1.f;  // c1
    scal[5 + 2 * g] = 2.f / lmax;        // c2
    scal[8 + g] = lmax;
  }
}

// ---------------- GEMM (MFMA, 128x128x32 tiles) ----------------
// out[row][col] epilogues:
//  MODE 0: Sp = acc - u_row*u_col/utu        (A=Mh[g], B=Mh[g], z-grid over g)
//  MODE 1: Z1 = c1*X - c2*acc                (A=Xh bf16)
//  MODE 2: Z2 = 2*(c1*Z1 - c2*acc) - X       (A=Z1 fp32, cvt-staged)
//  MODE 3: Z3 = 2*(c1*Z2 - c2*acc) - Z1      (A=Z2 fp32, cvt-staged)
template <int MODE>
__global__ __launch_bounds__(256) void k_gemm(
    const unsigned short* __restrict__ Abf, const float* __restrict__ Af,
    const unsigned short* __restrict__ Bmh, float* __restrict__ out,
    const unsigned short* __restrict__ Xh, const float* __restrict__ R1,
    const float* __restrict__ R2, const float* __restrict__ uvec,
    const float* __restrict__ scal, int g) {
  __shared__ __align__(16) unsigned short As[128 * 32];
  __shared__ __align__(16) unsigned short Bs[128 * 32];
  const int tid = threadIdx.x;
  const int lane = tid & 63;
  const int w = tid >> 6;
  const int wm = w >> 1, wn = w & 1;
  const int l15 = lane & 15, quad = lane >> 4;
  if (MODE == 0) {
    g = blockIdx.z;
    Abf += (size_t)g * NNq;
    Bmh += (size_t)g * NNq;
    out += (size_t)g * NNq;
  }
  const int row0 = blockIdx.y * 128;
  const int col0 = blockIdx.x * 128;
  const int c1i = tid, c2i = tid + 256;
  const int r1 = c1i >> 2, q1 = c1i & 3;
  const int r2 = c2i >> 2, q2 = c2i & 3;
  const size_t aoff1 = (size_t)(row0 + r1) * 2048 + q1 * 8;
  const size_t aoff2 = (size_t)(row0 + r2) * 2048 + q2 * 8;
  const size_t boff1 = (size_t)(col0 + r1) * 2048 + q1 * 8;
  const size_t boff2 = (size_t)(col0 + r2) * 2048 + q2 * 8;
  char* AsB = (char*)As;
  char* BsB = (char*)Bs;
  const unsigned ldsb1 = w * 1024u, ldsb2 = 4096u + w * 1024u;

  f32x4 acc[4][4];
#pragma unroll
  for (int i = 0; i < 4; i++)
#pragma unroll
    for (int j = 0; j < 4; j++) acc[i][j] = (f32x4){0.f, 0.f, 0.f, 0.f};

  for (int k0 = 0; k0 < 2048; k0 += 32) {
    __syncthreads();
    ald16(Bmh + boff1 + k0, BsB + ldsb1);
    ald16(Bmh + boff2 + k0, BsB + ldsb2);
    if (MODE <= 1) {
      ald16(Abf + aoff1 + k0, AsB + ldsb1);
      ald16(Abf + aoff2 + k0, AsB + ldsb2);
    } else {
      const float* p1 = Af + aoff1 + k0;
      const float* p2 = Af + aoff2 + k0;
      f32x4 x0 = *(const f32x4*)p1;
      f32x4 x1 = *(const f32x4*)(p1 + 4);
      f32x4 y0 = *(const f32x4*)p2;
      f32x4 y1 = *(const f32x4*)(p2 + 4);
      u16x4 a0 = {f2bf(x0.x), f2bf(x0.y), f2bf(x0.z), f2bf(x0.w)};
      u16x4 a1 = {f2bf(x1.x), f2bf(x1.y), f2bf(x1.z), f2bf(x1.w)};
      u16x4 b0 = {f2bf(y0.x), f2bf(y0.y), f2bf(y0.z), f2bf(y0.w)};
      u16x4 b1 = {f2bf(y1.x), f2bf(y1.y), f2bf(y1.z), f2bf(y1.w)};
      *(u16x4*)(AsB + c1i * 16) = a0;
      *(u16x4*)(AsB + c1i * 16 + 8) = a1;
      *(u16x4*)(AsB + c2i * 16) = b0;
      *(u16x4*)(AsB + c2i * 16 + 8) = b1;
    }
    __syncthreads();
    s16x8 af[4], bfr[4];
    const int kq = quad * 8;
#pragma unroll
    for (int i = 0; i < 4; i++)
      af[i] = *(const s16x8*)(As + (wm * 64 + i * 16 + l15) * 32 + kq);
#pragma unroll
    for (int j = 0; j < 4; j++)
      bfr[j] = *(const s16x8*)(Bs + (wn * 64 + j * 16 + l15) * 32 + kq);
#pragma unroll
    for (int i = 0; i < 4; i++)
#pragma unroll
      for (int j = 0; j < 4; j++)
        acc[i][j] = __builtin_amdgcn_mfma_f32_16x16x32_bf16(af[i], bfr[j], acc[i][j], 0, 0, 0);
  }
  float c1v = 0.f, c2v = 0.f, iu = 0.f;
  if (MODE >= 1) { c1v = scal[4 + 2 * g]; c2v = scal[5 + 2 * g]; }
  else iu = scal[2 + g];
#pragma unroll
  for (int i = 0; i < 4; i++) {
    const int rb = row0 + wm * 64 + i * 16 + quad * 4;
#pragma unroll
    for (int j = 0; j < 4; j++) {
      const int col = col0 + wn * 64 + j * 16 + l15;
#pragma unroll
      for (int r = 0; r < 4; r++) {
        const int row = rb + r;
        const size_t o = (size_t)row * 2048 + col;
        const float p = acc[i][j][r];
        if (MODE == 0) out[o] = p - uvec[g * N_ + row] * uvec[g * N_ + col] * iu;
        else if (MODE == 1) out[o] = c1v * bf2f(Xh[o]) - c2v * p;
        else if (MODE == 2) out[o] = 2.f * (c1v * R1[o] - c2v * p) - bf2f(Xh[o]);
        else out[o] = 2.f * (c1v * R1[o] - c2v * p) - R2[o];
      }
    }
  }
}

// ---------------- TCN conv (2x2 dilated causal over (N,L), MFMA per tap) ----------------
__global__ void k_tcn(const float* __restrict__ hin, const float* __restrict__ res,
                      float* __restrict__ hout, const float* __restrict__ tw,
                      const float* __restrict__ tb, int cv, int dil) {
  __shared__ __align__(16) unsigned short ht[10 * 14 * 32];  // [row 10][l 14 (2 pad)][c 32]
  const int lane = threadIdx.x;
  const int n0 = blockIdx.x * 8, b = blockIdx.y;
  const int l15 = lane & 15, quad = lane >> 4;
  // zero tile (pads + halo)
  for (int i = lane; i < 560; i += 64)
    ((s16x8*)ht)[i] = (s16x8){0, 0, 0, 0, 0, 0, 0, 0};
  // weight B-fragments in registers (tap t = dn*2+dl; kh=1-dn, kw=1-dl)
  s16x8 wf[4][2];
#pragma unroll
  for (int t = 0; t < 4; t++) {
    int dn = t >> 1, dl = t & 1;
    int kh = 1 - dn, kw = 1 - dl;
#pragma unroll
    for (int ot = 0; ot < 2; ot++) {
      int o = ot * 16 + l15;
      s16x8 f;
#pragma unroll
      for (int j = 0; j < 8; j++) {
        int ii = quad * 8 + j;
        f[j] = (short)f2bf(tw[(((cv * 32 + o) * 32 + ii) * 2 + kh) * 2 + kw]);
      }
      wf[t][ot] = f;
    }
  }
  float b0 = tb[cv * 32 + l15], b1 = tb[cv * 32 + 16 + l15];
  __syncthreads();
  // fill interior
  for (int e = lane; e < 960; e += 64) {
    int r = e / 96;
    int rem = e % 96;
    int l = rem >> 3, q = rem & 7;
    int n = n0 - 2 + r;
    if (n >= 0) {
      f32x4 v = *(const f32x4*)(hin + (((size_t)b * N_ + n) * L_ + l) * C_ + q * 4);
      u16x4 h4;
      h4.x = f2bf(v.x); h4.y = f2bf(v.y); h4.z = f2bf(v.z); h4.w = f2bf(v.w);
      *(u16x4*)(ht + (r * 14 + l + 2) * 32 + q * 4) = h4;
    }
  }
  __syncthreads();
  f32x4 acc[6][2];
#pragma unroll
  for (int mt = 0; mt < 6; mt++) { acc[mt][0] = (f32x4){0,0,0,0}; acc[mt][1] = (f32x4){0,0,0,0}; }
#pragma unroll
  for (int mt = 0; mt < 6; mt++) {
    int m = mt * 16 + l15;
    int pn = m / 12, pl = m % 12;
#pragma unroll
    for (int t = 0; t < 4; t++) {
      int dn = t >> 1, dl = t & 1;
      int rr = pn + 2 - dn * dil;
      int ll = pl + 2 - dl * dil;
      s16x8 a = *(const s16x8*)(ht + (rr * 14 + ll) * 32 + quad * 8);
      acc[mt][0] = __builtin_amdgcn_mfma_f32_16x16x32_bf16(a, wf[t][0], acc[mt][0], 0, 0, 0);
      acc[mt][1] = __builtin_amdgcn_mfma_f32_16x16x32_bf16(a, wf[t][1], acc[mt][1], 0, 0, 0);
    }
  }
#pragma unroll
  for (int mt = 0; mt < 6; mt++) {
#pragma unroll
    for (int ot = 0; ot < 2; ot++) {
      float bb = ot ? b1 : b0;
      int o = ot * 16 + l15;
#pragma unroll
      for (int r = 0; r < 4; r++) {
        int m = mt * 16 + quad * 4 + r;
        int pn = m / 12, pl = m % 12;
        size_t oi = (((size_t)b * N_ + n0 + pn) * L_ + pl) * C_ + o;
        float v = fmaxf(acc[mt][ot][r] + bb, 0.f);
        if (res) v += res[oi];
        hout[oi] = v;
      }
    }
  }
}

// ---------------- transpose x_gcn -> Xh bf16 [F][N] ----------------
__global__ void k_transpose(const float* __restrict__ xg, unsigned short* __restrict__ Xh) {
  __shared__ float t[64][65];
  int n0 = blockIdx.x * 64, f0 = blockIdx.y * 64, b = blockIdx.z;
  int tid = threadIdx.x;
  int lr = tid >> 4, lc = tid & 15;
#pragma unroll
  for (int p = 0; p < 4; p++) {
    int row = p * 16 + lr;
    f32x4 v = *(const f32x4*)(xg + ((size_t)b * N_ + n0 + row) * 384 + f0 + lc * 4);
    t[row][lc * 4 + 0] = v.x; t[row][lc * 4 + 1] = v.y;
    t[row][lc * 4 + 2] = v.z; t[row][lc * 4 + 3] = v.w;
  }
  __syncthreads();
#pragma unroll
  for (int p = 0; p < 4; p++) {
    int fr = p * 16 + lr;
    u16x4 o;
    o.x = f2bf(t[lc * 4 + 0][fr]); o.y = f2bf(t[lc * 4 + 1][fr]);
    o.z = f2bf(t[lc * 4 + 2][fr]); o.w = f2bf(t[lc * 4 + 3][fr]);
    *(u16x4*)(Xh + (size_t)(b * 384 + f0 + fr) * N_ + n0 + lc * 4) = o;
  }
}

// ---------------- projection: G = (relu of) sum_k Z_k W_k + bias ----------------
__global__ void k_proj(const unsigned short* __restrict__ Xh, const float* __restrict__ Z1,
                       const float* __restrict__ Z2, const float* __restrict__ Z3,
                       const float* __restrict__ W, const float* __restrict__ bias,
                       float* __restrict__ G, int addmode) {
  int n = blockIdx.x * 128 + threadIdx.x;
  int bl = blockIdx.y;
  size_t base = (size_t)bl * 32 * 2048 + n;
  float acc[32];
#pragma unroll
  for (int o = 0; o < 32; o++) acc[o] = bias[o];
  for (int c = 0; c < 32; c++) {
    size_t idx = base + (size_t)c * 2048;
    float x0 = bf2f(Xh[idx]);
    float z1 = Z1[idx];
    float z2 = Z2[idx];
    float z3 = Z3[idx];
    const float* w0 = W + c * 32;
#pragma unroll
    for (int o = 0; o < 32; o++)
      acc[o] += x0 * w0[o] + z1 * w0[1024 + o] + z2 * w0[2048 + o] + z3 * w0[3072 + o];
  }
#pragma unroll
  for (int o = 0; o < 32; o++) {
    float v = fmaxf(acc[o], 0.f);
    size_t oi = base + (size_t)o * 2048;
    if (addmode) G[oi] += v; else G[oi] = v;
  }
}

// ---------------- final gate fusion (in-place on d_out) ----------------
__global__ void k_final(float* __restrict__ outp, const float* __restrict__ G,
                        const float* __restrict__ gw, const float* __restrict__ gb) {
  __shared__ float Fg[32][65];
  __shared__ float Ot[64][33];
  int n0 = blockIdx.x * 64;
  int bl = blockIdx.y;
  int b = bl / 12, l = bl % 12;
  int tid = threadIdx.x;
  for (int e = tid; e < 2048; e += 256) {
    int j = e >> 6, nl = e & 63;
    Fg[j][nl] = G[(size_t)(bl * 32 + j) * 2048 + n0 + nl];
  }
  for (int e = tid; e < 2048; e += 256) {
    int nl = e >> 5, j = e & 31;
    Ot[nl][j] = outp[(((size_t)b * N_ + n0 + nl) * L_ + l) * C_ + j];
  }
  __syncthreads();
  int o = tid & 31;
  float gwa[64];
#pragma unroll
  for (int j = 0; j < 64; j++) gwa[j] = gw[j * 32 + o];
  float gbv = gb[o];
  for (int rep = 0; rep < 8; rep++) {
    int nl = (tid >> 5) + rep * 8;
    float s = gbv;
#pragma unroll
    for (int j = 0; j < 32; j++)
      s += Fg[j][nl] * gwa[j] + Ot[nl][j] * gwa[32 + j];
    float gate = 1.f / (1.f + __expf(-s));
    float og = Fg[o][nl], ot = Ot[nl][o];
    outp[(((size_t)b * N_ + n0 + nl) * L_ + l) * C_ + o] =
        fmaxf(gate * ot + (1.f - gate) * og, 0.f);
  }
}

extern "C" void kernel_launch(void* const* d_in, const int* in_sizes, int n_in,
                              void* d_out, int out_size, void* d_ws, size_t ws_size,
                              hipStream_t stream) {
  const float* x_gcn = (const float*)d_in[0];
  const float* x_tcn = (const float*)d_in[1];
  const float* graphs = (const float*)d_in[2];
  const float* W_f = (const float*)d_in[3];
  const float* b_f = (const float*)d_in[4];
  const float* W_g = (const float*)d_in[5];
  const float* b_g = (const float*)d_in[6];
  const float* tcn_w = (const float*)d_in[7];
  const float* tcn_b = (const float*)d_in[8];
  const float* gate_w = (const float*)d_in[9];
  const float* gate_b = (const float*)d_in[10];
  float* out = (float*)d_out;

  char* ws = (char*)d_ws;
  const size_t NF4 = (size_t)NFq * 4;  // 50331648
  const size_t NF2 = NF4 / 2;
  const size_t REQ = 4 * NF4 + NF2 + (size_t)2 * NNq * 2 + 65536;
  if (ws_size < REQ) return;  // insufficient workspace

  float* Za = (float*)ws;
  float* Zb = (float*)(ws + NF4);
  float* Zc = (float*)(ws + 2 * NF4);
  float* Gf = (float*)(ws + 3 * NF4);
  float* Sp = Gf;  // Sp (2*NN fp32 = 33.5MB) reuses Gf region before proj runs
  unsigned short* Xh = (unsigned short*)(ws + 4 * NF4);
  unsigned short* Mh = (unsigned short*)(ws + 4 * NF4 + NF2);
  char* sm = ws + 4 * NF4 + NF2 + (size_t)2 * NNq * 2;
  float* deg = (float*)sm;
  float* dinv = deg + 2 * N_;
  float* uv = dinv + 2 * N_;
  float* pv = uv + 2 * N_;
  float* py = pv + 2 * N_;
  float* scal = py + 2 * N_;

  // ---- lmax pipeline ----
  k_deg<<<dim3(N_, 2), 256, 0, stream>>>(graphs, deg, dinv, uv);
  k_utu<<<2, 256, 0, stream>>>(deg, scal);
  k_initv<<<dim3(8, 2), 256, 0, stream>>>(pv);
  k_buildM<<<dim3(N_, 2), 256, 0, stream>>>(graphs, dinv, Mh);
  k_gemm<0><<<dim3(16, 16, 2), 256, 0, stream>>>(Mh, nullptr, Mh, Sp, nullptr, nullptr,
                                                 nullptr, uv, scal, 0);
  float* a = pv;
  float* bv = py;
  for (int i = 0; i < 40; i++) {
    k_matvec<<<dim3(512, 2), 256, 0, stream>>>(Sp, a, bv, 3072.f);
    float* t = a; a = bv; bv = t;
  }
  k_matvec<<<dim3(512, 2), 256, 0, stream>>>(Sp, a, bv, 1.f);
  k_rayleigh<<<2, 256, 0, stream>>>(a, bv, scal);

  // ---- TCN (out_tcn lands in d_out) ----
  k_tcn<<<dim3(256, 16), 64, 0, stream>>>(x_tcn, nullptr, Za, tcn_w, tcn_b, 0, 1);
  k_tcn<<<dim3(256, 16), 64, 0, stream>>>(Za, x_tcn, Zb, tcn_w, tcn_b, 1, 1);
  k_tcn<<<dim3(256, 16), 64, 0, stream>>>(Zb, nullptr, Za, tcn_w, tcn_b, 2, 2);
  k_tcn<<<dim3(256, 16), 64, 0, stream>>>(Za, Zb, out, tcn_w, tcn_b, 3, 2);

  // ---- GCN ----
  k_transpose<<<dim3(32, 6, 16), 256, 0, stream>>>(x_gcn, Xh);
  for (int g = 0; g < 2; g++) {
    const unsigned short* Bg = Mh + (size_t)g * NNq;
    k_gemm<1><<<dim3(16, 48), 256, 0, stream>>>(Xh, nullptr, Bg, Za, Xh, nullptr, nullptr,
                                                nullptr, scal, g);
    k_gemm<2><<<dim3(16, 48), 256, 0, stream>>>(nullptr, Za, Bg, Zb, Xh, Za, nullptr,
                                                nullptr, scal, g);
    k_gemm<3><<<dim3(16, 48), 256, 0, stream>>>(nullptr, Zb, Bg, Zc, nullptr, Zb, Za,
                                                nullptr, scal, g);
    k_proj<<<dim3(16, 192), 128, 0, stream>>>(Xh, Za, Zb, Zc, g ? W_g : W_f,
                                              g ? b_g : b_f, Gf, g);
  }
  k_final<<<dim3(32, 192), 256, 0, stream>>>(out, Gf, gate_w, gate_b);
  (void)in_sizes; (void)n_in; (void)out_size;
}

// Round 2
// 1106.265 us; speedup vs baseline: 1.5219x; 1.5219x over previous
//
#include <hip/hip_runtime.h>

#define DI __device__ __forceinline__

typedef __attribute__((ext_vector_type(4))) float f32x4;
typedef __attribute__((ext_vector_type(8))) short s16x8;
typedef __attribute__((ext_vector_type(4))) unsigned short u16x4;

constexpr int B_ = 16, N_ = 2048, L_ = 12, C_ = 32;
constexpr int F_ = B_ * L_ * C_;              // 6144
constexpr long long NNq = (long long)N_ * N_; // 4194304
constexpr long long NFq = (long long)N_ * F_; // 12582912

DI unsigned short f2bf(float x) {
  unsigned u = __float_as_uint(x);
  u += 0x7fffu + ((u >> 16) & 1u);
  return (unsigned short)(u >> 16);
}
DI float bf2f(unsigned short h) { return __uint_as_float(((unsigned)h) << 16); }

typedef __attribute__((address_space(3))) void* lds_vp;
typedef const __attribute__((address_space(1))) void* gbl_vp;
DI void ald16(const void* g, void* l) {
  __builtin_amdgcn_global_load_lds((gbl_vp)g, (lds_vp)l, 16, 0, 0);
}

// ---------------- degree / dinv / u ----------------
__global__ void k_deg(const float* __restrict__ graphs, float* deg, float* dinv, float* uv) {
  int n = blockIdx.x, g = blockIdx.y;
  const float* row = graphs + (size_t)g * NNq + (size_t)n * N_;
  float s = 0.f;
  for (int m = threadIdx.x * 4; m < N_; m += 1024) {
    f32x4 v = *(const f32x4*)(row + m);
    s += v.x + v.y + v.z + v.w;
  }
  for (int o = 32; o; o >>= 1) s += __shfl_down(s, o);
  __shared__ float warr[4];
  int lane = threadIdx.x & 63, w = threadIdx.x >> 6;
  if (!lane) warr[w] = s;
  __syncthreads();
  if (!threadIdx.x) {
    float t = warr[0] + warr[1] + warr[2] + warr[3];
    deg[g * N_ + n] = t;
    dinv[g * N_ + n] = rsqrtf(t);
    uv[g * N_ + n] = sqrtf(t);
  }
}

__global__ void k_utu(const float* __restrict__ deg, float* scal) {
  int g = blockIdx.x;
  float s = 0.f;
  for (int n = threadIdx.x; n < N_; n += 256) s += deg[g * N_ + n];
  for (int o = 32; o; o >>= 1) s += __shfl_down(s, o);
  __shared__ float warr[4];
  int lane = threadIdx.x & 63, w = threadIdx.x >> 6;
  if (!lane) warr[w] = s;
  __syncthreads();
  if (!threadIdx.x) {
    float t = warr[0] + warr[1] + warr[2] + warr[3];
    scal[g] = t;
    scal[2 + g] = 1.f / t;
  }
}

__global__ void k_initv(float* v) {
  int i = blockIdx.x * 256 + threadIdx.x;
  int g = blockIdx.y;
  unsigned h = (unsigned)(i + g * 7919) * 2654435761u;
  h ^= h >> 16; h *= 2246822519u; h ^= h >> 13;
  float r = ((float)(h & 0xFFFFu) / 32768.f) - 1.f;
  if (r == 0.f) r = 0.5f;
  v[g * N_ + i] = r;
}

__global__ void k_buildM(const float* __restrict__ graphs, const float* __restrict__ dinv,
                         unsigned short* __restrict__ Mh) {
  int n = blockIdx.x, g = blockIdx.y;
  const float* row = graphs + (size_t)g * NNq + (size_t)n * N_;
  unsigned short* orow = Mh + (size_t)g * NNq + (size_t)n * N_;
  float dn = dinv[g * N_ + n];
  const float* dm = dinv + g * N_;
  for (int m = threadIdx.x * 4; m < N_; m += 1024) {
    f32x4 a = *(const f32x4*)(row + m);
    f32x4 d = *(const f32x4*)(dm + m);
    u16x4 o;
    o.x = f2bf(a.x * dn * d.x); o.y = f2bf(a.y * dn * d.y);
    o.z = f2bf(a.z * dn * d.z); o.w = f2bf(a.w * dn * d.w);
    *(u16x4*)(orow + m) = o;
  }
}

// ---------------- power iteration (Sp stored bf16) ----------------
__global__ void k_matvec(const unsigned short* __restrict__ Sph, const float* __restrict__ vin,
                         float* __restrict__ vout, float scale) {
  int g = blockIdx.y;
  int row = blockIdx.x * 4 + (threadIdx.x >> 6);
  int lane = threadIdx.x & 63;
  const unsigned short* r = Sph + (size_t)g * NNq + (size_t)row * N_;
  const float* v = vin + g * N_;
  float s = 0.f;
  for (int m = lane * 8; m < N_; m += 512) {
    s16x8 a = *(const s16x8*)(r + m);
    f32x4 b0 = *(const f32x4*)(v + m);
    f32x4 b1 = *(const f32x4*)(v + m + 4);
    s += bf2f((unsigned short)a[0]) * b0.x + bf2f((unsigned short)a[1]) * b0.y +
         bf2f((unsigned short)a[2]) * b0.z + bf2f((unsigned short)a[3]) * b0.w +
         bf2f((unsigned short)a[4]) * b1.x + bf2f((unsigned short)a[5]) * b1.y +
         bf2f((unsigned short)a[6]) * b1.z + bf2f((unsigned short)a[7]) * b1.w;
  }
  for (int o = 32; o; o >>= 1) s += __shfl_down(s, o);
  if (!lane) vout[g * N_ + row] = s * scale;
}

__global__ void k_rayleigh(const float* __restrict__ v, const float* __restrict__ y,
                           float* scal) {
  int g = blockIdx.x;
  double sn = 0.0, sd = 0.0;
  for (int i = threadIdx.x; i < N_; i += 256) {
    double a = v[g * N_ + i], b = y[g * N_ + i];
    sn += a * b; sd += a * a;
  }
  for (int o = 32; o; o >>= 1) { sn += __shfl_down(sn, o); sd += __shfl_down(sd, o); }
  __shared__ double wn[4], wd[4];
  int lane = threadIdx.x & 63, w = threadIdx.x >> 6;
  if (!lane) { wn[w] = sn; wd[w] = sd; }
  __syncthreads();
  if (!threadIdx.x) {
    double nn = wn[0] + wn[1] + wn[2] + wn[3];
    double dd = wd[0] + wd[1] + wd[2] + wd[3];
    double rho = nn / dd;
    if (!(rho > 0.0)) rho = 0.0;
    float R = (float)sqrt(rho);
    float lmax = 1.f + R;
    scal[4 + 2 * g] = 2.f / lmax - 1.f;  // c1
    scal[5 + 2 * g] = 2.f / lmax;        // c2
    scal[8 + g] = lmax;
  }
}

// ---------------- GEMM (MFMA, 128x128x32 tiles, all-bf16 operands+outputs) ----------------
//  MODE 0: Sp = acc - u_row*u_col/utu              (A=Mh[g], B=Mh[g], z over g) -> bf16
//  MODE 1: Z1 = c1*X - c2*acc                      (A=Xh)                       -> bf16
//  MODE 2: Z2 = 2*(c1*Z1 - c2*acc) - X             (A=Z1h, R1=Z1h)              -> bf16
//  MODE 3: Z3 = 2*(c1*Z2 - c2*acc) - Z1            (A=Z2h, R1=Z2h, R2=Z1h)      -> bf16
template <int MODE>
__global__ __launch_bounds__(256) void k_gemm(
    const unsigned short* __restrict__ Abf, const unsigned short* __restrict__ Bmh,
    unsigned short* __restrict__ outh,
    const unsigned short* __restrict__ Xh, const unsigned short* __restrict__ R1h,
    const unsigned short* __restrict__ R2h, const float* __restrict__ uvec,
    const float* __restrict__ scal, int g) {
  __shared__ __align__(16) unsigned short As[128 * 32];
  __shared__ __align__(16) unsigned short Bs[128 * 32];
  const int tid = threadIdx.x;
  const int lane = tid & 63;
  const int w = tid >> 6;
  const int wm = w >> 1, wn = w & 1;
  const int l15 = lane & 15, quad = lane >> 4;
  if (MODE == 0) {
    g = blockIdx.z;
    Abf += (size_t)g * NNq;
    Bmh += (size_t)g * NNq;
    outh += (size_t)g * NNq;
  }
  const int row0 = blockIdx.y * 128;
  const int col0 = blockIdx.x * 128;
  const int c1i = tid, c2i = tid + 256;
  const int r1 = c1i >> 2, q1 = c1i & 3;
  const int r2 = c2i >> 2, q2 = c2i & 3;
  const size_t aoff1 = (size_t)(row0 + r1) * 2048 + q1 * 8;
  const size_t aoff2 = (size_t)(row0 + r2) * 2048 + q2 * 8;
  const size_t boff1 = (size_t)(col0 + r1) * 2048 + q1 * 8;
  const size_t boff2 = (size_t)(col0 + r2) * 2048 + q2 * 8;
  char* AsB = (char*)As;
  char* BsB = (char*)Bs;
  const unsigned ldsb1 = w * 1024u, ldsb2 = 4096u + w * 1024u;

  f32x4 acc[4][4];
#pragma unroll
  for (int i = 0; i < 4; i++)
#pragma unroll
    for (int j = 0; j < 4; j++) acc[i][j] = (f32x4){0.f, 0.f, 0.f, 0.f};

  for (int k0 = 0; k0 < 2048; k0 += 32) {
    __syncthreads();
    ald16(Bmh + boff1 + k0, BsB + ldsb1);
    ald16(Bmh + boff2 + k0, BsB + ldsb2);
    ald16(Abf + aoff1 + k0, AsB + ldsb1);
    ald16(Abf + aoff2 + k0, AsB + ldsb2);
    __syncthreads();
    s16x8 af[4], bfr[4];
    const int kq = quad * 8;
#pragma unroll
    for (int i = 0; i < 4; i++)
      af[i] = *(const s16x8*)(As + (wm * 64 + i * 16 + l15) * 32 + kq);
#pragma unroll
    for (int j = 0; j < 4; j++)
      bfr[j] = *(const s16x8*)(Bs + (wn * 64 + j * 16 + l15) * 32 + kq);
#pragma unroll
    for (int i = 0; i < 4; i++)
#pragma unroll
      for (int j = 0; j < 4; j++)
        acc[i][j] = __builtin_amdgcn_mfma_f32_16x16x32_bf16(af[i], bfr[j], acc[i][j], 0, 0, 0);
  }
  float c1v = 0.f, c2v = 0.f, iu = 0.f;
  if (MODE >= 1) { c1v = scal[4 + 2 * g]; c2v = scal[5 + 2 * g]; }
  else iu = scal[2 + g];
#pragma unroll
  for (int i = 0; i < 4; i++) {
    const int rb = row0 + wm * 64 + i * 16 + quad * 4;
#pragma unroll
    for (int j = 0; j < 4; j++) {
      const int col = col0 + wn * 64 + j * 16 + l15;
#pragma unroll
      for (int r = 0; r < 4; r++) {
        const int row = rb + r;
        const size_t o = (size_t)row * 2048 + col;
        const float p = acc[i][j][r];
        float val;
        if (MODE == 0) val = p - uvec[g * N_ + row] * uvec[g * N_ + col] * iu;
        else if (MODE == 1) val = c1v * bf2f(Xh[o]) - c2v * p;
        else if (MODE == 2) val = 2.f * (c1v * bf2f(R1h[o]) - c2v * p) - bf2f(Xh[o]);
        else val = 2.f * (c1v * bf2f(R1h[o]) - c2v * p) - bf2f(R2h[o]);
        outh[o] = f2bf(val);
      }
    }
  }
}

// ---------------- TCN conv (2x2 dilated causal over (N,L), MFMA per tap) ----------------
__global__ void k_tcn(const float* __restrict__ hin, const float* __restrict__ res,
                      float* __restrict__ hout, const float* __restrict__ tw,
                      const float* __restrict__ tb, int cv, int dil) {
  __shared__ __align__(16) unsigned short ht[10 * 14 * 32];  // [row 10][l 14 (2 pad)][c 32]
  const int lane = threadIdx.x;
  const int n0 = blockIdx.x * 8, b = blockIdx.y;
  const int l15 = lane & 15, quad = lane >> 4;
  for (int i = lane; i < 560; i += 64)
    ((s16x8*)ht)[i] = (s16x8){0, 0, 0, 0, 0, 0, 0, 0};
  s16x8 wf[4][2];
#pragma unroll
  for (int t = 0; t < 4; t++) {
    int dn = t >> 1, dl = t & 1;
    int kh = 1 - dn, kw = 1 - dl;
#pragma unroll
    for (int ot = 0; ot < 2; ot++) {
      int o = ot * 16 + l15;
      s16x8 f;
#pragma unroll
      for (int j = 0; j < 8; j++) {
        int ii = quad * 8 + j;
        f[j] = (short)f2bf(tw[(((cv * 32 + o) * 32 + ii) * 2 + kh) * 2 + kw]);
      }
      wf[t][ot] = f;
    }
  }
  float b0 = tb[cv * 32 + l15], b1 = tb[cv * 32 + 16 + l15];
  __syncthreads();
  for (int e = lane; e < 960; e += 64) {
    int r = e / 96;
    int rem = e % 96;
    int l = rem >> 3, q = rem & 7;
    int n = n0 - 2 + r;
    if (n >= 0) {
      f32x4 v = *(const f32x4*)(hin + (((size_t)b * N_ + n) * L_ + l) * C_ + q * 4);
      u16x4 h4;
      h4.x = f2bf(v.x); h4.y = f2bf(v.y); h4.z = f2bf(v.z); h4.w = f2bf(v.w);
      *(u16x4*)(ht + (r * 14 + l + 2) * 32 + q * 4) = h4;
    }
  }
  __syncthreads();
  f32x4 acc[6][2];
#pragma unroll
  for (int mt = 0; mt < 6; mt++) { acc[mt][0] = (f32x4){0,0,0,0}; acc[mt][1] = (f32x4){0,0,0,0}; }
#pragma unroll
  for (int mt = 0; mt < 6; mt++) {
    int m = mt * 16 + l15;
    int pn = m / 12, pl = m % 12;
#pragma unroll
    for (int t = 0; t < 4; t++) {
      int dn = t >> 1, dl = t & 1;
      int rr = pn + 2 - dn * dil;
      int ll = pl + 2 - dl * dil;
      s16x8 a = *(const s16x8*)(ht + (rr * 14 + ll) * 32 + quad * 8);
      acc[mt][0] = __builtin_amdgcn_mfma_f32_16x16x32_bf16(a, wf[t][0], acc[mt][0], 0, 0, 0);
      acc[mt][1] = __builtin_amdgcn_mfma_f32_16x16x32_bf16(a, wf[t][1], acc[mt][1], 0, 0, 0);
    }
  }
#pragma unroll
  for (int mt = 0; mt < 6; mt++) {
#pragma unroll
    for (int ot = 0; ot < 2; ot++) {
      float bb = ot ? b1 : b0;
      int o = ot * 16 + l15;
#pragma unroll
      for (int r = 0; r < 4; r++) {
        int m = mt * 16 + quad * 4 + r;
        int pn = m / 12, pl = m % 12;
        size_t oi = (((size_t)b * N_ + n0 + pn) * L_ + pl) * C_ + o;
        float v = fmaxf(acc[mt][ot][r] + bb, 0.f);
        if (res) v += res[oi];
        hout[oi] = v;
      }
    }
  }
}

// ---------------- transpose x_gcn -> Xh bf16 [F][N] ----------------
__global__ void k_transpose(const float* __restrict__ xg, unsigned short* __restrict__ Xh) {
  __shared__ float t[64][65];
  int n0 = blockIdx.x * 64, f0 = blockIdx.y * 64, b = blockIdx.z;
  int tid = threadIdx.x;
  int lr = tid >> 4, lc = tid & 15;
#pragma unroll
  for (int p = 0; p < 4; p++) {
    int row = p * 16 + lr;
    f32x4 v = *(const f32x4*)(xg + ((size_t)b * N_ + n0 + row) * 384 + f0 + lc * 4);
    t[row][lc * 4 + 0] = v.x; t[row][lc * 4 + 1] = v.y;
    t[row][lc * 4 + 2] = v.z; t[row][lc * 4 + 3] = v.w;
  }
  __syncthreads();
#pragma unroll
  for (int p = 0; p < 4; p++) {
    int fr = p * 16 + lr;
    u16x4 o;
    o.x = f2bf(t[lc * 4 + 0][fr]); o.y = f2bf(t[lc * 4 + 1][fr]);
    o.z = f2bf(t[lc * 4 + 2][fr]); o.w = f2bf(t[lc * 4 + 3][fr]);
    *(u16x4*)(Xh + (size_t)(b * 384 + f0 + fr) * N_ + n0 + lc * 4) = o;
  }
}

// ---------------- projection: G = (relu of) sum_k Z_k W_k + bias (all-bf16 inputs) ----------
__global__ void k_proj(const unsigned short* __restrict__ Xh, const unsigned short* __restrict__ Z1,
                       const unsigned short* __restrict__ Z2, const unsigned short* __restrict__ Z3,
                       const float* __restrict__ W, const float* __restrict__ bias,
                       float* __restrict__ G, int addmode) {
  int n = blockIdx.x * 128 + threadIdx.x;
  int bl = blockIdx.y;
  size_t base = (size_t)bl * 32 * 2048 + n;
  float acc[32];
#pragma unroll
  for (int o = 0; o < 32; o++) acc[o] = bias[o];
  for (int c = 0; c < 32; c++) {
    size_t idx = base + (size_t)c * 2048;
    float x0 = bf2f(Xh[idx]);
    float z1 = bf2f(Z1[idx]);
    float z2 = bf2f(Z2[idx]);
    float z3 = bf2f(Z3[idx]);
    const float* w0 = W + c * 32;
#pragma unroll
    for (int o = 0; o < 32; o++)
      acc[o] += x0 * w0[o] + z1 * w0[1024 + o] + z2 * w0[2048 + o] + z3 * w0[3072 + o];
  }
#pragma unroll
  for (int o = 0; o < 32; o++) {
    float v = fmaxf(acc[o], 0.f);
    size_t oi = base + (size_t)o * 2048;
    if (addmode) G[oi] += v; else G[oi] = v;
  }
}

// ---------------- final gate fusion: MFMA gate GEMM, in-place on d_out ----------------
__global__ __launch_bounds__(256) void k_final(float* __restrict__ outp,
                                               const float* __restrict__ G,
                                               const float* __restrict__ gw,
                                               const float* __restrict__ gb) {
  __shared__ __align__(16) unsigned short fus[64][72];  // [nl][j] bf16 (j<32: gcn, j>=32: tcn)
  __shared__ __align__(16) unsigned short gwt[32][72];  // [o][j] bf16 (gw transposed)
  int n0 = blockIdx.x * 64;
  int bl = blockIdx.y;
  int b = bl / 12, l = bl % 12;
  int tid = threadIdx.x;
  // gw^T -> LDS
  for (int e = tid; e < 2048; e += 256) {
    int j = e >> 5, o = e & 31;
    gwt[o][j] = f2bf(gw[e]);
  }
  // out_gcn part (transposed): fus[nl][j] = G[(bl*32+j)][n0+nl]
  for (int e = tid; e < 2048; e += 256) {
    int j = e >> 6, nl = e & 63;
    fus[nl][j] = f2bf(G[(size_t)(bl * 32 + j) * 2048 + n0 + nl]);
  }
  // out_tcn part: fus[nl][32+j]
  for (int e = tid; e < 2048; e += 256) {
    int nl = e >> 5, j = e & 31;
    fus[nl][32 + j] = f2bf(outp[(((size_t)b * N_ + n0 + nl) * L_ + l) * C_ + j]);
  }
  __syncthreads();
  int lane = tid & 63, w = tid >> 6;
  int l15 = lane & 15, quad = lane >> 4;
  f32x4 acc[2];
  acc[0] = (f32x4){0.f, 0.f, 0.f, 0.f};
  acc[1] = (f32x4){0.f, 0.f, 0.f, 0.f};
#pragma unroll
  for (int ks = 0; ks < 2; ks++) {
    s16x8 a = *(const s16x8*)&fus[w * 16 + l15][ks * 32 + quad * 8];
#pragma unroll
    for (int nt = 0; nt < 2; nt++) {
      s16x8 bfr = *(const s16x8*)&gwt[nt * 16 + l15][ks * 32 + quad * 8];
      acc[nt] = __builtin_amdgcn_mfma_f32_16x16x32_bf16(a, bfr, acc[nt], 0, 0, 0);
    }
  }
#pragma unroll
  for (int nt = 0; nt < 2; nt++) {
    int o = nt * 16 + l15;
    float gbv = gb[o];
#pragma unroll
    for (int r = 0; r < 4; r++) {
      int nl = w * 16 + quad * 4 + r;
      float s = acc[nt][r] + gbv;
      float gate = 1.f / (1.f + __expf(-s));
      float og = bf2f(fus[nl][o]);
      float ot = bf2f(fus[nl][32 + o]);
      outp[(((size_t)b * N_ + n0 + nl) * L_ + l) * C_ + o] =
          fmaxf(gate * ot + (1.f - gate) * og, 0.f);
    }
  }
}

extern "C" void kernel_launch(void* const* d_in, const int* in_sizes, int n_in,
                              void* d_out, int out_size, void* d_ws, size_t ws_size,
                              hipStream_t stream) {
  const float* x_gcn = (const float*)d_in[0];
  const float* x_tcn = (const float*)d_in[1];
  const float* graphs = (const float*)d_in[2];
  const float* W_f = (const float*)d_in[3];
  const float* b_f = (const float*)d_in[4];
  const float* W_g = (const float*)d_in[5];
  const float* b_g = (const float*)d_in[6];
  const float* tcn_w = (const float*)d_in[7];
  const float* tcn_b = (const float*)d_in[8];
  const float* gate_w = (const float*)d_in[9];
  const float* gate_b = (const float*)d_in[10];
  float* out = (float*)d_out;

  char* ws = (char*)d_ws;
  const size_t NF4 = (size_t)NFq * 4;   // 50331648
  const size_t NF2 = (size_t)NFq * 2;   // 25165824
  const size_t NN2 = (size_t)NNq * 2 * 2;  // 16777216 (2 graphs bf16)
  const size_t REQ = 3 * NF4 + NF2 + 2 * NN2 + 65536;
  if (ws_size < REQ) return;

  float* Za = (float*)ws;                    // TCN tmp; later Z1h/Z2h
  float* Zb = (float*)(ws + NF4);            // TCN tmp; later Z3h
  float* Gf = (float*)(ws + 2 * NF4);        // fused gcn output (fp32)
  unsigned short* Xh = (unsigned short*)(ws + 3 * NF4);
  unsigned short* Mh = (unsigned short*)(ws + 3 * NF4 + NF2);
  unsigned short* Sph = (unsigned short*)(ws + 3 * NF4 + NF2 + NN2);
  char* sm = ws + 3 * NF4 + NF2 + 2 * NN2;
  float* deg = (float*)sm;
  float* dinv = deg + 2 * N_;
  float* uv = dinv + 2 * N_;
  float* pv = uv + 2 * N_;
  float* py = pv + 2 * N_;
  float* scal = py + 2 * N_;

  unsigned short* Z1h = (unsigned short*)Za;
  unsigned short* Z2h = (unsigned short*)(ws + NF2);
  unsigned short* Z3h = (unsigned short*)Zb;

  // ---- lmax pipeline ----
  k_deg<<<dim3(N_, 2), 256, 0, stream>>>(graphs, deg, dinv, uv);
  k_utu<<<2, 256, 0, stream>>>(deg, scal);
  k_initv<<<dim3(8, 2), 256, 0, stream>>>(pv);
  k_buildM<<<dim3(N_, 2), 256, 0, stream>>>(graphs, dinv, Mh);
  k_gemm<0><<<dim3(16, 16, 2), 256, 0, stream>>>(Mh, Mh, Sph, nullptr, nullptr, nullptr,
                                                 uv, scal, 0);
  float* a = pv;
  float* bv = py;
  for (int i = 0; i < 12; i++) {
    k_matvec<<<dim3(512, 2), 256, 0, stream>>>(Sph, a, bv, 3072.f);
    float* t = a; a = bv; bv = t;
  }
  k_matvec<<<dim3(512, 2), 256, 0, stream>>>(Sph, a, bv, 1.f);
  k_rayleigh<<<2, 256, 0, stream>>>(a, bv, scal);

  // ---- TCN (out_tcn lands in d_out) ----
  k_tcn<<<dim3(256, 16), 64, 0, stream>>>(x_tcn, nullptr, Za, tcn_w, tcn_b, 0, 1);
  k_tcn<<<dim3(256, 16), 64, 0, stream>>>(Za, x_tcn, Zb, tcn_w, tcn_b, 1, 1);
  k_tcn<<<dim3(256, 16), 64, 0, stream>>>(Zb, nullptr, Za, tcn_w, tcn_b, 2, 2);
  k_tcn<<<dim3(256, 16), 64, 0, stream>>>(Za, Zb, out, tcn_w, tcn_b, 3, 2);

  // ---- GCN ----
  k_transpose<<<dim3(32, 6, 16), 256, 0, stream>>>(x_gcn, Xh);
  for (int g = 0; g < 2; g++) {
    const unsigned short* Bg = Mh + (size_t)g * NNq;
    k_gemm<1><<<dim3(16, 48), 256, 0, stream>>>(Xh, Bg, Z1h, Xh, nullptr, nullptr,
                                                nullptr, scal, g);
    k_gemm<2><<<dim3(16, 48), 256, 0, stream>>>(Z1h, Bg, Z2h, Xh, Z1h, nullptr,
                                                nullptr, scal, g);
    k_gemm<3><<<dim3(16, 48), 256, 0, stream>>>(Z2h, Bg, Z3h, nullptr, Z2h, Z1h,
                                                nullptr, scal, g);
    k_proj<<<dim3(16, 192), 128, 0, stream>>>(Xh, Z1h, Z2h, Z3h, g ? W_g : W_f,
                                              g ? b_g : b_f, Gf, g);
  }
  k_final<<<dim3(32, 192), 256, 0, stream>>>(out, Gf, gate_w, gate_b);
  (void)in_sizes; (void)n_in; (void)out_size;
}